// Round 16
// baseline (2528.162 us; speedup 1.0000x reference)
//
#include <hip/hip_runtime.h>
#include <hip/hip_bf16.h>
#include <cstdint>

typedef __bf16 bf16_t;
typedef __bf16 bf16x4 __attribute__((ext_vector_type(4)));
typedef __bf16 bf16x8 __attribute__((ext_vector_type(8)));
typedef float f32x4 __attribute__((ext_vector_type(4)));

#define BATCH 4096
#define DIN   1024
#define HID   2048
#define DOUT  1000
#define NITER 50
#define LR    0.001f

#define BM 64
#define BN 128
#define BK 32
#define NBUF 3

// async global -> LDS, 16 B per lane. LDS dest is wave-uniform base + lane*16.
#define GLDS(g, l)                                                        \
    __builtin_amdgcn_global_load_lds(                                     \
        (const __attribute__((address_space(1))) void*)(g),               \
        (__attribute__((address_space(3))) void*)(l), 16, 0, 0)

#define WAITVM(N) asm volatile("s_waitcnt vmcnt(" #N ")" ::: "memory")
#define BAR()     __builtin_amdgcn_s_barrier()
#define SCHEDB()  __builtin_amdgcn_sched_barrier(0)

// ---------------------------------------------------------------------------
// R15 champion (1853 us) with 4 barrier groups per CU.
// UZ GEMM blocks: 256 thr / 4 waves, tile 64x128 (wave tile 64x32 acc[4][2]),
// LDS 36 KB (NBUF=3) -> 4 blocks/CU; grid 1024 = exactly 4/CU -> 16 waves/CU
// in 4 INDEPENDENT barrier groups (R15 had 2).  R9-R14 showed group count is
// the dominant latency-hiding variable; this moves it 2 -> 4.
// K-loop: single-tile depth-3 (R4-proven), 3 loads/tile (1 A + 2 B),
// steady WAITVM(6), tail 6 -> 3 -> 0.
// Mapping: m = bid & 63 (A-panel peers stride 64 = 0 mod 8 -> same XCD),
// sub = bid >> 6; role = sub>>3 (0: U, Bt=Wg; 1: Z, Bt=Wc); n0 = (sub&7)*BN.
// States bf16 (R15-proven): u, z, ey, xbf.
//   U: u += LR*D; e_x' = x - sigmoid(u) -> dst; energy += e^2
//   Z: z += LR*D; e_y' = (1+LR)e_y - LR*D; last iter y = (1+LR)e_y + z
// MODE: 0 = UZ, 1 = UZ first (seed from biases), 2 = Z-only final (grid 512).
// ---------------------------------------------------------------------------
template <int MODE>
__global__ __launch_bounds__(256) void pc_gemm(
    const bf16_t* __restrict__ Aex,
    const bf16_t* __restrict__ wg, const bf16_t* __restrict__ wc,
    const bf16_t* __restrict__ xbf, const float* __restrict__ bias_g,
    const float* __restrict__ bias_o,
    bf16_t* __restrict__ exnext, bf16_t* __restrict__ u,
    bf16_t* __restrict__ z, bf16_t* __restrict__ ey,
    float* __restrict__ yout, float* __restrict__ energy)
{
    __shared__ __align__(16) bf16_t sA[NBUF][BM * BK];
    __shared__ __align__(16) bf16_t sB[NBUF][BN * BK];
    __shared__ float red[4];

    const int t    = threadIdx.x;
    const int lane = t & 63;
    const int wave = t >> 6;        // 0..3 (also the wave's 32-col slot)
    const int bid  = blockIdx.x;
    const int m    = bid & 63;      // A-panel id; peers stride 64 -> same XCD
    const int sub  = bid >> 6;      // 0..15 (MODE 0/1) or 0..7 (MODE 2)
    const int role = (MODE == 2) ? 1 : (sub >> 3);
    const int n0   = (MODE == 2) ? sub * BN : (sub & 7) * BN;
    const int m0   = m * BM;
    const int lr   = lane & 15;
    const int lkb  = (lane >> 4) * 8;
    const int prow = (lane >> 4) * 4;

    const bf16_t* Bop = role ? wc : wg;

    // staging: A (64x32, 4KB): wave w rows [16w,16w+16); 1 load/thread
    //          B (128x32, 8KB): wave w rows [32w,32w+32); 2 loads/thread
    const int srow = lane >> 2;          // 0..15
    const int scol = (lane & 3) * 8;
    const bf16_t* gA  = Aex + (int64_t)(m0 + wave * 16 + srow) * DIN + scol;
    const bf16_t* gB0 = Bop + (int64_t)(n0 + wave * 32 + srow) * DIN + scol;
    const bf16_t* gB1 = gB0 + (int64_t)16 * DIN;

    f32x4 acc[4][2] = {};

    auto stage = [&](int tile, int buf) {
        const int64_t ko = (int64_t)tile * BK;
        GLDS(gA  + ko, &sA[buf][wave * 512]);
        GLDS(gB0 + ko, &sB[buf][wave * 1024]);
        GLDS(gB1 + ko, &sB[buf][wave * 1024 + 512]);
    };
    auto compute = [&](int buf) {
        bf16x8 af[4], bfr[2];
#pragma unroll
        for (int mi = 0; mi < 4; ++mi)
            af[mi] = *reinterpret_cast<const bf16x8*>(
                &sA[buf][(mi * 16 + lr) * BK + lkb]);
#pragma unroll
        for (int ni = 0; ni < 2; ++ni)
            bfr[ni] = *reinterpret_cast<const bf16x8*>(
                &sB[buf][(wave * 32 + ni * 16 + lr) * BK + lkb]);
#pragma unroll
        for (int mi = 0; mi < 4; ++mi)
#pragma unroll
            for (int ni = 0; ni < 2; ++ni)
                acc[mi][ni] = __builtin_amdgcn_mfma_f32_16x16x32_bf16(
                    af[mi], bfr[ni], acc[mi][ni], 0, 0, 0);
    };

    const int nt = DIN / BK;               // 32
    stage(0, 0); stage(1, 1); stage(2, 2); // 9 loads in flight

    for (int ts = 0; ts < nt - 3; ++ts) {
        WAITVM(6);               // tile ts landed; ts+1, ts+2 flying
        BAR();
        SCHEDB();
        compute(ts % 3);
        BAR();
        stage(ts + 3, ts % 3);   // back to 9; never drain to 0 in loop
    }
    WAITVM(6); BAR(); SCHEDB(); compute((nt - 3) % 3);
    WAITVM(3); BAR(); SCHEDB(); compute((nt - 2) % 3);
    WAITVM(0); BAR(); SCHEDB(); compute((nt - 1) % 3);

    // epilogue: C mapping col=lane&15, row=(lane>>4)*4+j
    float esum = 0.0f;
#pragma unroll
    for (int mi = 0; mi < 4; ++mi) {
#pragma unroll
        for (int ni = 0; ni < 2; ++ni) {
            const int col = n0 + wave * 32 + ni * 16 + lr;
#pragma unroll
            for (int j = 0; j < 4; ++j) {
                const int row = m0 + mi * 16 + prow + j;
                const float v = acc[mi][ni][j];
                const float D = LR * v;
                if (role == 0) {
                    const int64_t idx = (int64_t)row * DIN + col;
                    const float un =
                        (MODE == 1 ? bias_g[col] : (float)u[idx]) + D;
                    u[idx] = (bf16_t)un;
                    const float xp = 1.0f / (1.0f + __expf(-un));
                    const float e  = (float)xbf[idx] - xp;
                    exnext[idx] = (bf16_t)e;
                    esum += e * e;
                } else if (col < DOUT) {
                    const int64_t idx = (int64_t)row * 1024 + col;
                    const float zn =
                        (MODE == 1 ? bias_o[col] : (float)z[idx]) + D;
                    const float eyn = (MODE == 1)
                        ? -zn
                        : (1.0f + LR) * (float)ey[idx] - D;
                    if constexpr (MODE == 2) {
                        yout[(int64_t)row * DOUT + col] =
                            (1.0f + LR) * eyn + zn;
                    } else {
                        z[idx]  = (bf16_t)zn;
                        ey[idx] = (bf16_t)eyn;
                    }
                    esum += eyn * eyn;
                }
            }
        }
    }
#pragma unroll
    for (int off = 32; off; off >>= 1) esum += __shfl_down(esum, off, 64);
    if (lane == 0) red[wave] = esum;
    __syncthreads();
    if (t == 0)
        atomicAdd(energy, red[0] + red[1] + red[2] + red[3]);
}

// ---------------------------------------------------------------------------
// setup: Wg = W_rec^T W_rec (role 0), Wc = W_out W_rec (role 1); K = 2048.
// R9-proven 512-thread GEMM core, plain C-store epilogue.  Runs once.
// ---------------------------------------------------------------------------
__global__ __launch_bounds__(512) void setup_gemm(
    const bf16_t* __restrict__ wrecT, const bf16_t* __restrict__ woutP,
    bf16_t* __restrict__ wg, bf16_t* __restrict__ wc)
{
    __shared__ __align__(16) bf16_t sA[4][128 * BK];
    __shared__ __align__(16) bf16_t sB[4][128 * BK];

    const int t    = threadIdx.x;
    const int lane = t & 63;
    const int wave = t >> 6;
    const int wm   = wave >> 2;
    const int wn   = wave & 3;
    const int m0   = blockIdx.x * 128;
    const int role = (int)blockIdx.y >= 8;
    const int n0   = ((int)blockIdx.y & 7) * 128;
    const int lr   = lane & 15;
    const int lkb  = (lane >> 4) * 8;
    const int prow = (lane >> 4) * 4;

    f32x4 acc[4][2] = {};

    const int srow = wave * 16 + (lane >> 2);
    const int scol = (lane & 3) * 8;
    const bf16_t* gA = (role ? woutP : wrecT) + (int64_t)(m0 + srow) * HID + scol;
    const bf16_t* gB = wrecT + (int64_t)(n0 + srow) * HID + scol;

    auto stage = [&](int tile, int buf) {
        const int64_t ko = (int64_t)tile * BK;
        GLDS(gA + ko, &sA[buf][wave * 512]);
        GLDS(gB + ko, &sB[buf][wave * 512]);
    };
    auto compute = [&](int buf) {
        bf16x8 af[4], bfr[2];
#pragma unroll
        for (int mi = 0; mi < 4; ++mi)
            af[mi] = *reinterpret_cast<const bf16x8*>(
                &sA[buf][(wm * 64 + mi * 16 + lr) * BK + lkb]);
#pragma unroll
        for (int ni = 0; ni < 2; ++ni)
            bfr[ni] = *reinterpret_cast<const bf16x8*>(
                &sB[buf][(wn * 32 + ni * 16 + lr) * BK + lkb]);
#pragma unroll
        for (int mi = 0; mi < 4; ++mi)
#pragma unroll
            for (int ni = 0; ni < 2; ++ni)
                acc[mi][ni] = __builtin_amdgcn_mfma_f32_16x16x32_bf16(
                    af[mi], bfr[ni], acc[mi][ni], 0, 0, 0);
    };

    const int npairs = (HID / BK) / 2;   // 32
    stage(0, 0); stage(1, 1); stage(2, 2); stage(3, 3);
    for (int p = 0; p < npairs - 2; ++p) {
        const int t0 = 2 * p;
        WAITVM(4); BAR(); SCHEDB();
        compute(t0 & 3); compute((t0 + 1) & 3);
        BAR();
        stage(t0 + 4, t0 & 3); stage(t0 + 5, (t0 + 1) & 3);
    }
    {
        const int t0 = 2 * npairs - 4;
        WAITVM(4); BAR(); SCHEDB();
        compute(t0 & 3); compute((t0 + 1) & 3);
    }
    {
        const int t0 = 2 * npairs - 2;
        WAITVM(0); BAR(); SCHEDB();
        compute(t0 & 3); compute((t0 + 1) & 3);
    }

    bf16_t* cout = role ? wc : wg;
#pragma unroll
    for (int mi = 0; mi < 4; ++mi)
#pragma unroll
        for (int ni = 0; ni < 2; ++ni) {
            const int col = n0 + wn * 32 + ni * 16 + lr;
#pragma unroll
            for (int j = 0; j < 4; ++j) {
                const int row = m0 + wm * 64 + mi * 16 + prow + j;
                cout[(int64_t)row * 1024 + col] = (bf16_t)acc[mi][ni][j];
            }
        }
}

// W_rec [HID][DIN] f32 -> bf16 transpose [DIN][HID]
__global__ void conv_wrec(const float* __restrict__ W, bf16_t* __restrict__ WbT)
{
    __shared__ float tile[32][33];
    const int tx = threadIdx.x & 31;
    const int ty = threadIdx.x >> 5; // 0..7
    const int c0 = blockIdx.x * 32;  // DIN
    const int r0 = blockIdx.y * 32;  // HID
#pragma unroll
    for (int rr = ty; rr < 32; rr += 8)
        tile[rr][tx] = W[(int64_t)(r0 + rr) * DIN + c0 + tx];
    __syncthreads();
#pragma unroll
    for (int rr = ty; rr < 32; rr += 8)
        WbT[(int64_t)(c0 + rr) * HID + r0 + tx] = (bf16_t)tile[tx][rr];
}

// W_out [DOUT][HID] f32 -> bf16 [1024][HID], rows >= DOUT zero-padded
__global__ void conv_wout(const float* __restrict__ W, bf16_t* __restrict__ Wb)
{
    const int i = blockIdx.x * 256 + threadIdx.x; // over 1024*2048
    const int r = i >> 11;
    const int c = i & 2047;
    Wb[i] = (r < DOUT) ? (bf16_t)W[(int64_t)r * HID + c] : (bf16_t)0.0f;
}

// iteration 0: e_x0 = x - sigmoid(b_gen) (+ energy); also x -> bf16 copy
__global__ void ex0_kernel(const float* __restrict__ x,
                           const float* __restrict__ bias_g,
                           bf16_t* __restrict__ ex, bf16_t* __restrict__ xbf,
                           float* __restrict__ energy)
{
    __shared__ float red[4];
    const int t = threadIdx.x, lane = t & 63, wave = t >> 6;
    const int i = (blockIdx.x * 256 + t) * 4;
    const int c0 = i & (DIN - 1);
    const float4 v = *reinterpret_cast<const float4*>(&x[i]);
    bf16x4 xo = {(bf16_t)v.x, (bf16_t)v.y, (bf16_t)v.z, (bf16_t)v.w};
    *reinterpret_cast<bf16x4*>(&xbf[i]) = xo;
    float e[4];
    const float b0 = bias_g[c0], b1 = bias_g[c0 + 1],
                b2 = bias_g[c0 + 2], b3 = bias_g[c0 + 3];
    e[0] = v.x - 1.0f / (1.0f + __expf(-b0));
    e[1] = v.y - 1.0f / (1.0f + __expf(-b1));
    e[2] = v.z - 1.0f / (1.0f + __expf(-b2));
    e[3] = v.w - 1.0f / (1.0f + __expf(-b3));
    bf16x4 o = {(bf16_t)e[0], (bf16_t)e[1], (bf16_t)e[2], (bf16_t)e[3]};
    *reinterpret_cast<bf16x4*>(&ex[i]) = o;
    float esum = e[0]*e[0] + e[1]*e[1] + e[2]*e[2] + e[3]*e[3];
#pragma unroll
    for (int off = 32; off; off >>= 1) esum += __shfl_down(esum, off, 64);
    if (lane == 0) red[wave] = esum;
    __syncthreads();
    if (t == 0) atomicAdd(energy, red[0] + red[1] + red[2] + red[3]);
}

__global__ void finalize_kernel(const float* __restrict__ energy,
                                float* __restrict__ out)
{
    out[0] = energy[0] * (1.0f / ((float)BATCH * (float)NITER));
}

extern "C" void kernel_launch(void* const* d_in, const int* in_sizes, int n_in,
                              void* d_out, int out_size, void* d_ws, size_t ws_size,
                              hipStream_t stream)
{
    (void)in_sizes; (void)n_in; (void)out_size; (void)ws_size;
    const float* x        = (const float*)d_in[0];
    const float* W_rec    = (const float*)d_in[1];
    const float* W_out    = (const float*)d_in[2];
    const float* bias_out = (const float*)d_in[3];
    const float* bias_gen = (const float*)d_in[4];
    float* y = (float*)d_out; // [BATCH*DOUT] then [1] energy

    char* ws = (char*)d_ws;
    size_t off = 0;
    bf16_t* u     = (bf16_t*)(ws + off);  off += (size_t)BATCH * DIN * 2;   // 8 MB
    bf16_t* z     = (bf16_t*)(ws + off);  off += (size_t)BATCH * 1024 * 2;  // 8 MB
    bf16_t* exA   = (bf16_t*)(ws + off);  off += (size_t)BATCH * DIN * 2;   // 8 MB
    bf16_t* exB   = (bf16_t*)(ws + off);  off += (size_t)BATCH * DIN * 2;   // 8 MB
    bf16_t* ey    = (bf16_t*)(ws + off);  off += (size_t)BATCH * 1024 * 2;  // 8 MB
    bf16_t* xbf   = (bf16_t*)(ws + off);  off += (size_t)BATCH * DIN * 2;   // 8 MB
    bf16_t* wrecT = (bf16_t*)(ws + off);  off += (size_t)DIN * HID * 2;     // 4 MB
    bf16_t* woutP = (bf16_t*)(ws + off);  off += (size_t)1024 * HID * 2;    // 4 MB
    bf16_t* wg    = (bf16_t*)(ws + off);  off += (size_t)1024 * 1024 * 2;   // 2 MB
    bf16_t* wc    = (bf16_t*)(ws + off);  off += (size_t)1024 * 1024 * 2;   // 2 MB
    float* energy = (float*)(ws + off);   off += 256;                       // 60 MB

    hipMemsetAsync(energy, 0, 4, stream);

    conv_wrec<<<dim3(DIN / 32, HID / 32), 256, 0, stream>>>(W_rec, wrecT);
    conv_wout<<<(1024 * HID) / 256, 256, 0, stream>>>(W_out, woutP);
    setup_gemm<<<dim3(8, 16), 512, 0, stream>>>(wrecT, woutP, wg, wc);
    ex0_kernel<<<(BATCH * DIN) / 1024, 256, 0, stream>>>(x, bias_gen, exA,
                                                         xbf, energy);

    bf16_t* exbuf[2] = {exA, exB};
    for (int it = 0; it < NITER; ++it) {
        const bf16_t* src = exbuf[it & 1];
        bf16_t* dst = exbuf[(it & 1) ^ 1];
        if (it == 0)
            pc_gemm<1><<<dim3(1024), 256, 0, stream>>>(
                src, wg, wc, xbf, bias_gen, bias_out,
                dst, u, z, ey, nullptr, energy);
        else if (it < NITER - 1)
            pc_gemm<0><<<dim3(1024), 256, 0, stream>>>(
                src, wg, wc, xbf, bias_gen, bias_out,
                dst, u, z, ey, nullptr, energy);
        else
            pc_gemm<2><<<dim3(512), 256, 0, stream>>>(
                src, wg, wc, xbf, bias_gen, bias_out,
                nullptr, u, z, ey, y, energy);
    }
    finalize_kernel<<<1, 1, 0, stream>>>(energy, y + (size_t)BATCH * DOUT);
}

// Round 17
// 1815.966 us; speedup vs baseline: 1.3922x; 1.3922x over previous
//
#include <hip/hip_runtime.h>
#include <hip/hip_bf16.h>
#include <cstdint>

typedef __bf16 bf16_t;
typedef __bf16 bf16x4 __attribute__((ext_vector_type(4)));
typedef __bf16 bf16x8 __attribute__((ext_vector_type(8)));
typedef float f32x4 __attribute__((ext_vector_type(4)));

#define BATCH 4096
#define DIN   1024
#define HID   2048
#define DOUT  1000
#define NITER 50
#define LR    0.001f

#define BM 128
#define BN 128
#define BK 32
#define NBUF 4

// async global -> LDS, 16 B per lane. LDS dest is wave-uniform base + lane*16.
#define GLDS(g, l)                                                        \
    __builtin_amdgcn_global_load_lds(                                     \
        (const __attribute__((address_space(1))) void*)(g),               \
        (__attribute__((address_space(3))) void*)(l), 16, 0, 0)

#define WAITVM(N) asm volatile("s_waitcnt vmcnt(" #N ")" ::: "memory")
#define BAR()     __builtin_amdgcn_s_barrier()
#define SCHEDB()  __builtin_amdgcn_sched_barrier(0)

// ---------------------------------------------------------------------------
// R15 champion (1853 us) + LDS slot-rotation swizzle (single variable).
// R16 data: dispatch time ~ linear in phase count; per-phase cost dominated by
// LDS fragment reads (192 KB/CU/phase = 1500cy floor) DOUBLED by an 8-way
// bank conflict: lanes 0-15 read col-slot g=const of 64B-stride rows ->
// 2 bank-starts.  Fix: rotate k-chunk slot within each row: s' = (g+(row>>1))&3.
// Because fragment rows are base+lr with base % 16 == 0, this reduces to pure
// LANE CONSTANTS:
//   read slot  = ((lane>>4) + ((lane>>1)&3)) & 3   (x8 elems, was (lane>>4)*8)
//   write side = GLDS linear dest + permuted global source chunk
//                g = ((lane&3) - ((lane>>3)&3)) & 3  (x8 elems, was (lane&3)*8)
// Zero extra per-phase instructions; coalescing unchanged (row-quads fetch the
// same 64B segment, internally permuted).  16-lane groups now spread over 8
// bank-starts (2-way = free, m136).
// Everything else IDENTICAL to R15 (modes, epilogues, bf16 states, grid).
// ---------------------------------------------------------------------------
template <int MODE>
__global__ __launch_bounds__(512) void pc_gemm(
    const bf16_t* __restrict__ Aex, bf16_t* __restrict__ wrecT,
    bf16_t* __restrict__ woutP, bf16_t* __restrict__ wg,
    bf16_t* __restrict__ wc,
    const bf16_t* __restrict__ xbf, const float* __restrict__ bias_g,
    const float* __restrict__ bias_o,
    bf16_t* __restrict__ exnext, bf16_t* __restrict__ u,
    bf16_t* __restrict__ z, bf16_t* __restrict__ ey,
    float* __restrict__ yout, float* __restrict__ energy)
{
    __shared__ __align__(16) bf16_t sA[NBUF][BM * BK];
    __shared__ __align__(16) bf16_t sB[NBUF][BN * BK];
    __shared__ float red[8];

    const int t    = threadIdx.x;
    const int lane = t & 63;
    const int wave = t >> 6;        // 0..7
    const int wm   = wave >> 2;     // wave row (0..1) -> 64 rows
    const int wn   = wave & 3;      // wave col (0..3) -> 32 cols
    const int m0   = blockIdx.x * BM;
    const int lr   = lane & 15;
    // swizzled read slot (lane constant): s' = ((g + (row>>1)) & 3) * 8
    const int lkb  = (((lane >> 4) + ((lane >> 1) & 3)) & 3) * 8;

    int role, n0, K;
    const bf16_t *Aop, *Bop;
    if constexpr (MODE == 3) {
        role = (int)blockIdx.y >= 8; n0 = ((int)blockIdx.y & 7) * BN; K = HID;
        Aop = role ? woutP : wrecT;  Bop = wrecT;
    } else if constexpr (MODE == 2) {
        role = 1; n0 = (int)blockIdx.y * BN; K = DIN;
        Aop = Aex; Bop = wc;
    } else {
        role = (int)blockIdx.y >= 8; n0 = ((int)blockIdx.y & 7) * BN; K = DIN;
        Aop = Aex; Bop = role ? wc : wg;
    }

    f32x4 acc[4][2] = {};

    // staging: lane l of wave w writes LDS slot (row = w*16 + l/4, s = l&3)
    // linearly; the slot must CONTAIN k-chunk g = (s - f(row))&3 with
    // f(row) = (row>>1)&3 = (l>>3)&3 (lane constant) -> permuted source col.
    const int srow = wave * 16 + (lane >> 2);
    const int gsrc = ((lane & 3) - ((lane >> 3) & 3)) & 3;
    const int scol = gsrc * 8;
    const bf16_t* gA = Aop + (int64_t)(m0 + srow) * K + scol;
    const bf16_t* gB = Bop + (int64_t)(n0 + srow) * K + scol;

    auto stage = [&](int tile, int buf) {
        const int64_t ko = (int64_t)tile * BK;
        GLDS(gA + ko, &sA[buf][wave * 512]);
        GLDS(gB + ko, &sB[buf][wave * 512]);
    };

    auto compute = [&](int buf) {
        bf16x8 af[4], bfr[2];
#pragma unroll
        for (int mi = 0; mi < 4; ++mi)
            af[mi] = *reinterpret_cast<const bf16x8*>(
                &sA[buf][(wm * 64 + mi * 16 + lr) * BK + lkb]);
#pragma unroll
        for (int ni = 0; ni < 2; ++ni)
            bfr[ni] = *reinterpret_cast<const bf16x8*>(
                &sB[buf][(wn * 32 + ni * 16 + lr) * BK + lkb]);
#pragma unroll
        for (int mi = 0; mi < 4; ++mi)
#pragma unroll
            for (int ni = 0; ni < 2; ++ni)
                acc[mi][ni] = __builtin_amdgcn_mfma_f32_16x16x32_bf16(
                    af[mi], bfr[ni], acc[mi][ni], 0, 0, 0);
    };

    const int npairs = (K / BK) / 2;       // 16 (UZ) or 32 (setup)
    stage(0, 0); stage(1, 1); stage(2, 2); stage(3, 3);

    for (int p = 0; p < npairs - 2; ++p) {
        const int t0 = 2 * p;
        WAITVM(4);               // pair p landed; pair p+1 still flying
        BAR();
        SCHEDB();
        compute(t0 & 3);
        compute((t0 + 1) & 3);
        BAR();
        stage(t0 + 4, t0 & 3);   // vmcnt never drains to 0 in loop
        stage(t0 + 5, (t0 + 1) & 3);
    }
    {
        const int t0 = 2 * npairs - 4;
        WAITVM(4); BAR(); SCHEDB();
        compute(t0 & 3); compute((t0 + 1) & 3);
    }
    {
        const int t0 = 2 * npairs - 2;
        WAITVM(0); BAR(); SCHEDB();
        compute(t0 & 3); compute((t0 + 1) & 3);
    }

    // epilogue: C mapping col=lane&15, row=(lane>>4)*4+j
    float esum = 0.0f;
    const int prow = (lane >> 4) * 4;
#pragma unroll
    for (int mi = 0; mi < 4; ++mi) {
#pragma unroll
        for (int ni = 0; ni < 2; ++ni) {
            const int col = n0 + wn * 32 + ni * 16 + lr;
#pragma unroll
            for (int j = 0; j < 4; ++j) {
                const int row = m0 + wm * 64 + mi * 16 + prow + j;
                const float v = acc[mi][ni][j];
                if constexpr (MODE == 3) {
                    bf16_t* cout = role ? wc : wg;
                    cout[(int64_t)row * 1024 + col] = (bf16_t)v;
                } else {
                    if (role == 0) {
                        // U role: u += LR*v; e_x' = x - sigmoid(u); energy
                        const int64_t idx = (int64_t)row * DIN + col;
                        const float D  = LR * v;
                        const float un =
                            (MODE == 1 ? bias_g[col] : (float)u[idx]) + D;
                        u[idx] = (bf16_t)un;
                        const float xp = 1.0f / (1.0f + __expf(-un));
                        const float e  = (float)xbf[idx] - xp;
                        exnext[idx] = (bf16_t)e;
                        esum += e * e;
                    } else if (col < DOUT) {
                        // Z role: z += D; e_y = (1+LR)e_y - D; energy
                        const int64_t idx = (int64_t)row * 1024 + col;
                        const float D  = LR * v;
                        const float zn =
                            (MODE == 1 ? bias_o[col] : (float)z[idx]) + D;
                        const float eyn = (MODE == 1)
                            ? -zn
                            : (1.0f + LR) * (float)ey[idx] - D;
                        if constexpr (MODE == 2) {
                            yout[(int64_t)row * DOUT + col] =
                                (1.0f + LR) * eyn + zn;
                        } else {
                            z[idx]  = (bf16_t)zn;
                            ey[idx] = (bf16_t)eyn;
                        }
                        esum += eyn * eyn;
                    }
                }
            }
        }
    }
    if constexpr (MODE != 3) {
#pragma unroll
        for (int off = 32; off; off >>= 1) esum += __shfl_down(esum, off, 64);
        if (lane == 0) red[wave] = esum;
        __syncthreads();
        if (t == 0) {
            float s = 0.0f;
#pragma unroll
            for (int w = 0; w < 8; ++w) s += red[w];
            atomicAdd(energy, s);
        }
    }
}

// W_rec [HID][DIN] f32 -> bf16 transpose [DIN][HID]
__global__ void conv_wrec(const float* __restrict__ W, bf16_t* __restrict__ WbT)
{
    __shared__ float tile[32][33];
    const int tx = threadIdx.x & 31;
    const int ty = threadIdx.x >> 5; // 0..7
    const int c0 = blockIdx.x * 32;  // DIN
    const int r0 = blockIdx.y * 32;  // HID
#pragma unroll
    for (int rr = ty; rr < 32; rr += 8)
        tile[rr][tx] = W[(int64_t)(r0 + rr) * DIN + c0 + tx];
    __syncthreads();
#pragma unroll
    for (int rr = ty; rr < 32; rr += 8)
        WbT[(int64_t)(c0 + rr) * HID + r0 + tx] = (bf16_t)tile[tx][rr];
}

// W_out [DOUT][HID] f32 -> bf16 [1024][HID], rows >= DOUT zero-padded
__global__ void conv_wout(const float* __restrict__ W, bf16_t* __restrict__ Wb)
{
    const int i = blockIdx.x * 256 + threadIdx.x; // over 1024*2048
    const int r = i >> 11;
    const int c = i & 2047;
    Wb[i] = (r < DOUT) ? (bf16_t)W[(int64_t)r * HID + c] : (bf16_t)0.0f;
}

// iteration 0: e_x0 = x - sigmoid(b_gen) (+ energy); also x -> bf16 copy
__global__ void ex0_kernel(const float* __restrict__ x,
                           const float* __restrict__ bias_g,
                           bf16_t* __restrict__ ex, bf16_t* __restrict__ xbf,
                           float* __restrict__ energy)
{
    __shared__ float red[4];
    const int t = threadIdx.x, lane = t & 63, wave = t >> 6;
    const int i = (blockIdx.x * 256 + t) * 4;
    const int c0 = i & (DIN - 1);
    const float4 v = *reinterpret_cast<const float4*>(&x[i]);
    bf16x4 xo = {(bf16_t)v.x, (bf16_t)v.y, (bf16_t)v.z, (bf16_t)v.w};
    *reinterpret_cast<bf16x4*>(&xbf[i]) = xo;
    float e[4];
    const float b0 = bias_g[c0], b1 = bias_g[c0 + 1],
                b2 = bias_g[c0 + 2], b3 = bias_g[c0 + 3];
    e[0] = v.x - 1.0f / (1.0f + __expf(-b0));
    e[1] = v.y - 1.0f / (1.0f + __expf(-b1));
    e[2] = v.z - 1.0f / (1.0f + __expf(-b2));
    e[3] = v.w - 1.0f / (1.0f + __expf(-b3));
    bf16x4 o = {(bf16_t)e[0], (bf16_t)e[1], (bf16_t)e[2], (bf16_t)e[3]};
    *reinterpret_cast<bf16x4*>(&ex[i]) = o;
    float esum = e[0]*e[0] + e[1]*e[1] + e[2]*e[2] + e[3]*e[3];
#pragma unroll
    for (int off = 32; off; off >>= 1) esum += __shfl_down(esum, off, 64);
    if (lane == 0) red[wave] = esum;
    __syncthreads();
    if (t == 0) atomicAdd(energy, red[0] + red[1] + red[2] + red[3]);
}

__global__ void finalize_kernel(const float* __restrict__ energy,
                                float* __restrict__ out)
{
    out[0] = energy[0] * (1.0f / ((float)BATCH * (float)NITER));
}

extern "C" void kernel_launch(void* const* d_in, const int* in_sizes, int n_in,
                              void* d_out, int out_size, void* d_ws, size_t ws_size,
                              hipStream_t stream)
{
    (void)in_sizes; (void)n_in; (void)out_size; (void)ws_size;
    const float* x        = (const float*)d_in[0];
    const float* W_rec    = (const float*)d_in[1];
    const float* W_out    = (const float*)d_in[2];
    const float* bias_out = (const float*)d_in[3];
    const float* bias_gen = (const float*)d_in[4];
    float* y = (float*)d_out; // [BATCH*DOUT] then [1] energy

    char* ws = (char*)d_ws;
    size_t off = 0;
    bf16_t* u     = (bf16_t*)(ws + off);  off += (size_t)BATCH * DIN * 2;   // 8 MB
    bf16_t* z     = (bf16_t*)(ws + off);  off += (size_t)BATCH * 1024 * 2;  // 8 MB
    bf16_t* exA   = (bf16_t*)(ws + off);  off += (size_t)BATCH * DIN * 2;   // 8 MB
    bf16_t* exB   = (bf16_t*)(ws + off);  off += (size_t)BATCH * DIN * 2;   // 8 MB
    bf16_t* ey    = (bf16_t*)(ws + off);  off += (size_t)BATCH * 1024 * 2;  // 8 MB
    bf16_t* xbf   = (bf16_t*)(ws + off);  off += (size_t)BATCH * DIN * 2;   // 8 MB
    bf16_t* wrecT = (bf16_t*)(ws + off);  off += (size_t)DIN * HID * 2;     // 4 MB
    bf16_t* woutP = (bf16_t*)(ws + off);  off += (size_t)1024 * HID * 2;    // 4 MB
    bf16_t* wg    = (bf16_t*)(ws + off);  off += (size_t)1024 * 1024 * 2;   // 2 MB
    bf16_t* wc    = (bf16_t*)(ws + off);  off += (size_t)1024 * 1024 * 2;   // 2 MB
    float* energy = (float*)(ws + off);   off += 256;                       // 60 MB

    hipMemsetAsync(energy, 0, 4, stream);

    conv_wrec<<<dim3(DIN / 32, HID / 32), 256, 0, stream>>>(W_rec, wrecT);
    conv_wout<<<(1024 * HID) / 256, 256, 0, stream>>>(W_out, woutP);
    // setup: Wg = W_rec^T W_rec (y<8), Wc = W_out W_rec (y>=8), K = 2048
    pc_gemm<3><<<dim3(8, 16), 512, 0, stream>>>(
        nullptr, wrecT, woutP, wg, wc, nullptr, nullptr, nullptr,
        nullptr, nullptr, nullptr, nullptr, nullptr, nullptr);

    ex0_kernel<<<(BATCH * DIN) / 1024, 256, 0, stream>>>(x, bias_gen, exA,
                                                         xbf, energy);

    bf16_t* exbuf[2] = {exA, exB};
    for (int it = 0; it < NITER; ++it) {
        const bf16_t* src = exbuf[it & 1];
        bf16_t* dst = exbuf[(it & 1) ^ 1];
        if (it == 0)
            pc_gemm<1><<<dim3(BATCH / BM, 16), 512, 0, stream>>>(
                src, nullptr, nullptr, wg, wc, xbf, bias_gen, bias_out,
                dst, u, z, ey, nullptr, energy);
        else if (it < NITER - 1)
            pc_gemm<0><<<dim3(BATCH / BM, 16), 512, 0, stream>>>(
                src, nullptr, nullptr, wg, wc, xbf, bias_gen, bias_out,
                dst, u, z, ey, nullptr, energy);
        else
            pc_gemm<2><<<dim3(BATCH / BM, 8), 512, 0, stream>>>(
                src, nullptr, nullptr, wg, wc, xbf, bias_gen, bias_out,
                nullptr, u, z, ey, y, energy);
    }
    finalize_kernel<<<1, 1, 0, stream>>>(energy, y + (size_t)BATCH * DOUT);
}